// Round 3
// baseline (365.467 us; speedup 1.0000x reference)
//
#include <hip/hip_runtime.h>

#define B 256
#define N 512
#define M 512
#define BM (B * M)   // 131072

// Single self-sufficient kernel: block = output column m, 512 threads.
// No workspace, no transposes, no inter-block dependency.
//
// Per block:
//  stage 0: wcol[n]=w[n][m] (n=tid), tcol[b]=t[b][m]  (L2-resident gathers)
//  stage 1: stream x through LDS in 16 chunks of 16 b-rows (32 KB):
//           - rel_x numerator: f32 accum per z-chunk of 64 b (ascending b),
//             then p = ((z0+z1)+z2)+z3   [bit-identical to old px path]
//           - sum_x: f64 a0..a3 chains over b (b&3), (a0+a1)+(a2+a3) -> f32
//             [bit-identical to old sum_x block]
//  stage 1b: lanes 0..3 compute sum_w f64 4-chains over wcol (n&3 ascending)
//  stage 2: former k_col body verbatim, with
//             wT[m*N+n]  -> wcol[n] (= w[n*M+m], loaded at stage 0)
//             xT[n*B+b]  -> x[b*N+n]   (wave-uniform n, L2-hit gather)
//             tT[m*B+b]  -> t[b*M+m]
//             sum_w[m]   -> (float)((sw0+sw1)+(sw2+sw3))
//             worig      -> wcol

__global__ __launch_bounds__(512) void k_all(
        const float* __restrict__ x, const float* __restrict__ w,
        const float* __restrict__ t, float* __restrict__ out) {
    const int m = blockIdx.x, tid = threadIdx.x;
    const int lane = tid & 63, wid = tid >> 6;

    __shared__ float  s_x[16][512];                 // 32 KB x-chunk
    __shared__ float  tcol[256];
    __shared__ float  wcol[512];                    // doubles as worig
    __shared__ double swpart[4];
    __shared__ double bsumI[256];
    __shared__ double btot[4];
    __shared__ float  pm[512];
    __shared__ float  wsrt[512];
    __shared__ float  srx_r[512], srx_u[512];
    __shared__ int    srx_n[512];
    __shared__ int    cnt[256], cbase[256], cslot[256];
    __shared__ int    rcnt[256], rbase[256], rslot[256], rbmax[256];
    __shared__ float  wtotmax[8], red3[3][8];
    __shared__ int    ctot[4], rtot[4];

    // ---- stage 0: column loads (uncoalesced but L2-resident, once) ----
    const float wv = w[tid * M + m];                 // == old wT[m*N+tid]
    wcol[tid] = wv;
    if (tid < 256) {
        tcol[tid] = t[tid * M + m];
        cnt[tid] = 0; rcnt[tid] = 0; cslot[tid] = 0; rslot[tid] = 0; rbmax[tid] = 0;
    }
    __syncthreads();

    // ---- stage 1: stream x; thread tid owns column n = tid ----
    double a0 = 0, a1 = 0, a2 = 0, a3 = 0;           // sum_x f64 4-chain (b&3)
    float pzs0 = 0.f, pzs1 = 0.f, pzs2 = 0.f, pzs3 = 0.f;
    #pragma unroll
    for (int z = 0; z < 4; ++z) {                    // z-chunk of 64 b
        float pacc = 0.f;
        for (int cc = 0; cc < 4; ++cc) {             // 16-row sub-chunks
            const int c = z * 4 + cc;
            __syncthreads();
            #pragma unroll
            for (int k = 0; k < 4; ++k) {            // coalesced float4 fill
                const int row = k * 4 + (tid >> 7);
                const int col = (tid & 127) * 4;
                *(float4*)&s_x[row][col] =
                    *(const float4*)&x[(c * 16 + row) * N + col];
            }
            __syncthreads();
            #pragma unroll
            for (int r = 0; r < 16; ++r) {           // b ascending: bit-identical
                const float xv = s_x[r][tid];
                pacc += fminf(xv, tcol[c * 16 + r]);
                if      ((r & 3) == 0) a0 += (double)xv;
                else if ((r & 3) == 1) a1 += (double)xv;
                else if ((r & 3) == 2) a2 += (double)xv;
                else                   a3 += (double)xv;
            }
        }
        if      (z == 0) pzs0 = pacc;
        else if (z == 1) pzs1 = pacc;
        else if (z == 2) pzs2 = pacc;
        else             pzs3 = pacc;
    }
    float p = pzs0; p += pzs1; p += pzs2; p += pzs3; // same add order as k_col
    const float sxv = (float)((a0 + a1) + (a2 + a3));
    const float rv = p / sxv;

    // ---- stage 1b: sum_w f64 4-chains (lanes 0..3), order n&3 ascending ----
    if (tid < 4) {
        double a = 0.0;
        for (int n = tid; n < 512; n += 4) a += (double)wcol[n];
        swpart[tid] = a;
    }

    // ======================= stage 2: k_col verbatim =======================
    // ---- wave prefix-max (pm) + wave reductions (wmin,rmin,rmax) ----
    float pmv = wv;
    #pragma unroll
    for (int off = 1; off < 64; off <<= 1) {
        float o = __shfl_up(pmv, off, 64);
        if (lane >= off) pmv = fmaxf(pmv, o);
    }
    if (lane == 63) wtotmax[wid] = pmv;
    float wmn = wv, rmn = rv, rmx = rv;
    #pragma unroll
    for (int off = 32; off > 0; off >>= 1) {
        wmn = fminf(wmn, __shfl_xor(wmn, off, 64));
        rmn = fminf(rmn, __shfl_xor(rmn, off, 64));
        rmx = fmaxf(rmx, __shfl_xor(rmx, off, 64));
    }
    if (lane == 0) { red3[0][wid] = wmn; red3[1][wid] = rmn; red3[2][wid] = rmx; }
    __syncthreads();                                           // (1)

    {
        float om = -1e30f;
        for (int j = 0; j < wid; ++j) om = fmaxf(om, wtotmax[j]);
        pm[tid] = fmaxf(pmv, om);
    }
    float wmin = red3[0][0], rmin = red3[1][0], rmax = red3[2][0], wmax = wtotmax[0];
    #pragma unroll
    for (int j = 1; j < 8; ++j) {
        wmin = fminf(wmin, red3[0][j]);
        rmin = fminf(rmin, red3[1][j]);
        rmax = fmaxf(rmax, red3[2][j]);
        wmax = fmaxf(wmax, wtotmax[j]);
    }

    // ---- histograms ----
    const float wscale = 255.0f / fmaxf(wmax - wmin, 1e-30f);
    int wk = (int)((wv - wmin) * wscale);
    wk = wk < 0 ? 0 : (wk > 255 ? 255 : wk);
    atomicAdd(&cnt[wk], 1);
    const float rscale = 255.0f / fmaxf(rmax - rmin, 1e-30f);
    int rk;
    { int kv = (int)((rv - rmin) * rscale); kv = kv < 0 ? 0 : (kv > 255 ? 255 : kv); rk = 255 - kv; }
    atomicAdd(&rcnt[rk], 1);
    atomicMax(&rbmax[rk], __float_as_int(rv));                 // rv > 0
    __syncthreads();                                           // (2)

    // ---- both 256-prefix-sums concurrently: waves 0-3 cnt, waves 4-7 rcnt ----
    int myc = (tid < 256) ? cnt[tid] : rcnt[tid - 256];
    int incl = myc;
    #pragma unroll
    for (int off = 1; off < 64; off <<= 1) {
        int o = __shfl_up(incl, off, 64);
        if (lane >= off) incl += o;
    }
    if (lane == 63) { if (wid < 4) ctot[wid] = incl; else rtot[wid - 4] = incl; }
    __syncthreads();                                           // (3)
    if (tid < 256) {
        int eo = 0;
        for (int j = 0; j < wid; ++j) eo += ctot[j];
        cbase[tid] = eo + incl - myc;
    } else {
        int eo = 0, w2 = wid - 4;
        for (int j = 0; j < w2; ++j) eo += rtot[j];
        rbase[tid - 256] = eo + incl - myc;
    }
    __syncthreads();                                           // (4)

    // ---- scatter (bucket-ordered) ----
    { int p1 = cbase[wk] + atomicAdd(&cslot[wk], 1); wsrt[p1] = wv; }
    { int p2 = rbase[rk] + atomicAdd(&rslot[rk], 1);
      srx_r[p2] = rv; srx_n[p2] = tid; srx_u[p2] = __int_as_float(rbmax[rk]); }
    __syncthreads();                                           // (5)

    // ---- per-bucket f64 sums + 256-prefix (waves 0-3) ----
    double bincl = 0.0, mysum = 0.0;
    if (tid < 256) {
        int st = cbase[tid], e = st + cnt[tid];
        for (int i = st; i < e; ++i) mysum += (double)wsrt[i];
        bincl = mysum;
        #pragma unroll
        for (int off = 1; off < 64; off <<= 1) {
            double o = __shfl_up(bincl, off, 64);
            if (lane >= off) bincl += o;
        }
        if (lane == 63) btot[wid] = bincl;
    }
    __syncthreads();                                           // (6)
    if (tid < 256) {
        double eo = 0.0;
        for (int j = 0; j < wid; ++j) eo += btot[j];
        bsumI[tid] = eo + bincl;
    }
    __syncthreads();                                           // (7)

    if (tid < 256) {
        // ==== phase C: ind_w scan, descending-rel buckets (waves 0-3) ====
        const int b = tid;
        float bv = -1.0f; int bi = 0;
        for (int i = 0; i < 512; ++i) {
            float u = srx_u[i];                      // non-increasing bound
            if (__ballot(u >= bv) == 0ULL) break;
            float r = srx_r[i];
            int   n = srx_n[i];
            float xv = x[b * N + n];                 // wave-uniform n, L2-hit
            float v = fminf(xv, r);
            if (v > bv || (v == bv && n < bi)) { bv = v; bi = n; }
        }
        out[BM + b * M + m] = fminf(x[b * N + bi], wcol[bi]);    // chosen_w
    } else {
        // ==== phase D: rel_w CDF + ind_x (waves 4-7) ====
        const int b = tid - 256;
        const float tbm = t[b * M + m];              // == old tT[m*B+b]
        float btf = (tbm - wmin) * wscale;
        int kk; double S;
        if (btf < 0.0f) { kk = 0; S = 0.0; }
        else {
            int bt = (int)btf; bt = bt > 255 ? 255 : bt;
            kk = cbase[bt];
            S = (bt > 0) ? bsumI[bt - 1] : 0.0;
            int e = cbase[bt] + cnt[bt];
            for (int i = cbase[bt]; i < e; ++i) {
                float v = wsrt[i];
                if (v < tbm) { ++kk; S += (double)v; }
            }
        }
        double rw = S + (double)tbm * (double)(512 - kk);
        const float sw = (float)((swpart[0] + swpart[1]) + (swpart[2] + swpart[3]));
        float c = (float)rw / sw;
        float tgt = fminf(c, pm[511]);
        int lo = 0, hi = 511;
        while (lo < hi) { int mid = (lo + hi) >> 1; if (pm[mid] >= tgt) hi = mid; else lo = mid + 1; }
        const int ind = lo;
        out[b * M + m] = fminf(x[b * N + ind], wcol[ind]);       // chosen_x
    }
}

extern "C" void kernel_launch(void* const* d_in, const int* in_sizes, int n_in,
                              void* d_out, int out_size, void* d_ws, size_t ws_size,
                              hipStream_t stream) {
    const float* x = (const float*)d_in[0];  // (B, N)
    const float* w = (const float*)d_in[1];  // (N, M)
    const float* t = (const float*)d_in[2];  // (B, M)
    float* out = (float*)d_out;
    k_all<<<512, 512, 0, stream>>>(x, w, t, out);
}

// Round 4
// 253.528 us; speedup vs baseline: 1.4415x; 1.4415x over previous
//
#include <hip/hip_runtime.h>

#define B 256
#define N 512
#define M 512
#define BM (B * M)   // 131072
#define NM (N * M)   // 262144

// One ordinary kernel, 512 blocks x 512 threads, with a flag-based global
// barrier replacing the k_a | k_col dispatch boundary.
//
// Phase 1 (identical work/order to the proven round-0 k_a, remapped onto
// 512-thread blocks as two independent 256-thread halves):
//   blk 0..15   : xT tiles   (unit u = blk*2+half, 32 units)
//   blk 16..47  : wT tiles   (64 units)
//   blk 48..63  : tT tiles   (32 units)
//   blk 64      : sum_x (512 threads, 1 elem each, f64 4-chain by b&3)
//   blk 65      : sum_w (likewise over n)
//   blk 66..321 : relx units (512 units, 2 per block) -> px[z][m][n]
//   blk 322..511: no phase-1 work
// Barrier: __threadfence(); __syncthreads(); flags[blk]=1; every thread
//          spins on flags[tid] (512 threads cover 512 flags); bounded spin
//          so a residency surprise degrades to a wrong answer, not a hang.
//          grid=512 == 2 blocks/CU x 256 CU residency capacity.
// Phase 2: round-0 k_col body verbatim (m = blockIdx.x).

#define HALF_BYTES 16640          // transpose half: 64*65*4; relx half: 12800
#define SMEM_BYTES 33280

__device__ __forceinline__ void tile_tr256(const float* __restrict__ src,
                                           float* __restrict__ dst,
                                           int R, int C, int r0, int c0,
                                           int tl, char* hbase) {
    float (*s)[65] = reinterpret_cast<float (*)[65]>(hbase);
    const int tx = tl & 63, q = tl >> 6;
    #pragma unroll
    for (int j = 0; j < 16; ++j) {
        int rl = q * 16 + j;
        s[rl][tx] = src[(r0 + rl) * C + c0 + tx];
    }
    __syncthreads();
    #pragma unroll
    for (int j = 0; j < 16; ++j) {
        int cl = q * 16 + j;
        dst[(c0 + cl) * R + r0 + tx] = s[tx][cl];
    }
}

__global__ __launch_bounds__(512, 4) void k_fused(
        const float* __restrict__ x, const float* __restrict__ w,
        const float* __restrict__ t,
        float* __restrict__ xT, float* __restrict__ wT, float* __restrict__ tT,
        float* __restrict__ sum_x, float* __restrict__ sum_w,
        float* __restrict__ px, int* __restrict__ flags,
        float* __restrict__ out) {
    __shared__ __align__(16) char smem[SMEM_BYTES];
    const int blk = blockIdx.x, tid = threadIdx.x;
    const int half = tid >> 8, tl = tid & 255;
    char* hbase = smem + half * HALF_BYTES;

    // ======================= phase 1 =======================
    if (blk < 16) {
        const int u = blk * 2 + half;                        // 0..31
        tile_tr256(x, xT, B, N, (u >> 3) * 64, (u & 7) * 64, tl, hbase);
    } else if (blk < 48) {
        const int u = (blk - 16) * 2 + half;                 // 0..63
        tile_tr256(w, wT, N, M, (u >> 3) * 64, (u & 7) * 64, tl, hbase);
    } else if (blk < 64) {
        const int u = (blk - 48) * 2 + half;                 // 0..31
        tile_tr256(t, tT, B, M, (u >> 3) * 64, (u & 7) * 64, tl, hbase);
    } else if (blk == 64) {
        const int i = tid;
        double a0 = 0, a1 = 0, a2 = 0, a3 = 0;
        for (int b = 0; b < B; b += 4) {
            a0 += (double)x[(b + 0) * N + i];
            a1 += (double)x[(b + 1) * N + i];
            a2 += (double)x[(b + 2) * N + i];
            a3 += (double)x[(b + 3) * N + i];
        }
        sum_x[i] = (float)((a0 + a1) + (a2 + a3));
    } else if (blk == 65) {
        const int mm = tid;
        double a0 = 0, a1 = 0, a2 = 0, a3 = 0;
        for (int n = 0; n < N; n += 4) {
            a0 += (double)w[(n + 0) * M + mm];
            a1 += (double)w[(n + 1) * M + mm];
            a2 += (double)w[(n + 2) * M + mm];
            a3 += (double)w[(n + 3) * M + mm];
        }
        sum_w[mm] = (float)((a0 + a1) + (a2 + a3));
    } else if (blk < 322) {
        // ---- relx unit rb = (blk-66)*2 + half (0..511), round-0 body ----
        const int rb  = (blk - 66) * 2 + half;
        const int z   = rb >> 7;
        const int rem = rb & 127;
        const int m0 = (rem & 7) * 64;
        const int n0 = (rem >> 3) * 32;
        const int tx = tl & 15, ty = tl >> 4;
        float (*s_t)[64] = reinterpret_cast<float (*)[64]>(hbase);          // 8192
        float (*s_x)[36] = reinterpret_cast<float (*)[36]>(hbase + 8192);   // 4608
        const int sr = tl >> 3, sc = tl & 7;
        float aA0 = 0.f, aA1 = 0.f, aA2 = 0.f, aA3 = 0.f;
        float aB0 = 0.f, aB1 = 0.f, aB2 = 0.f, aB3 = 0.f;
        const int nA = ty * 2, nB = nA + 1;
        for (int scnk = 0; scnk < 2; ++scnk) {
            const int bb = z * 64 + scnk * 32;
            __syncthreads();
            *(float4*)&s_t[sr][sc * 8]     = *(const float4*)&t[(bb + sr) * M + m0 + sc * 8];
            *(float4*)&s_t[sr][sc * 8 + 4] = *(const float4*)&t[(bb + sr) * M + m0 + sc * 8 + 4];
            *(float4*)&s_x[sr][sc * 4]     = *(const float4*)&x[(bb + sr) * N + n0 + sc * 4];
            __syncthreads();
            #pragma unroll 8
            for (int i = 0; i < 32; ++i) {           // b ascending: bit-identical
                float4 tv = *(const float4*)&s_t[i][tx * 4];
                float xA = s_x[i][nA], xB = s_x[i][nB];
                aA0 += fminf(xA, tv.x); aA1 += fminf(xA, tv.y);
                aA2 += fminf(xA, tv.z); aA3 += fminf(xA, tv.w);
                aB0 += fminf(xB, tv.x); aB1 += fminf(xB, tv.y);
                aB2 += fminf(xB, tv.z); aB3 += fminf(xB, tv.w);
            }
        }
        __syncthreads();
        float* so = &s_t[0][0];                      // [m-local*32 + n-local]
        so[(tx * 4 + 0) * 32 + nA] = aA0; so[(tx * 4 + 0) * 32 + nB] = aB0;
        so[(tx * 4 + 1) * 32 + nA] = aA1; so[(tx * 4 + 1) * 32 + nB] = aB1;
        so[(tx * 4 + 2) * 32 + nA] = aA2; so[(tx * 4 + 2) * 32 + nB] = aB2;
        so[(tx * 4 + 3) * 32 + nA] = aA3; so[(tx * 4 + 3) * 32 + nB] = aB3;
        __syncthreads();
        const int m_l = tl >> 2, n_l = (tl & 3) * 8;
        float* dst = &px[z * NM + (m0 + m_l) * N + n0 + n_l];
        *(float4*)&dst[0] = *(const float4*)&so[m_l * 32 + n_l];
        *(float4*)&dst[4] = *(const float4*)&so[m_l * 32 + n_l + 4];
    }

    // ======================= global barrier =======================
    __threadfence();                                 // drain this thread's writes
    __syncthreads();                                 // whole block done
    if (tid == 0) atomicExch(&flags[blk], 1);        // release
    {
        int spins = 0;
        while (__hip_atomic_load(&flags[tid], __ATOMIC_RELAXED,
                                 __HIP_MEMORY_SCOPE_AGENT) == 0) {
            __builtin_amdgcn_s_sleep(2);
            if (++spins > (1 << 22)) break;          // fail-safe: no infinite hang
        }
    }
    __threadfence();                                 // acquire
    __syncthreads();                                 // also fences phase-1 LDS reuse

    // ======================= phase 2: k_col verbatim =======================
    const int m = blk;
    const int lane = tid & 63, wid = tid >> 6;

    double* bsumI   = (double*)(smem);                    // 2048
    double* btot    = (double*)(smem + 2048);             // 32
    float*  worig   = (float*)(smem + 2080);              // 2048
    float*  pm      = (float*)(smem + 4128);              // 2048
    float*  wsrt    = (float*)(smem + 6176);              // 2048
    float*  srx_r   = (float*)(smem + 8224);              // 2048
    float*  srx_u   = (float*)(smem + 10272);             // 2048
    int*    srx_n   = (int*)(smem + 12320);               // 2048
    int*    cnt     = (int*)(smem + 14368);               // 1024
    int*    cbase   = (int*)(smem + 15392);               // 1024
    int*    cslot   = (int*)(smem + 16416);               // 1024
    int*    rcnt    = (int*)(smem + 17440);               // 1024
    int*    rbase   = (int*)(smem + 18464);               // 1024
    int*    rslot   = (int*)(smem + 19488);               // 1024
    int*    rbmax   = (int*)(smem + 20512);               // 1024
    float*  wtotmax = (float*)(smem + 21536);             // 32
    float (*red3)[8] = (float (*)[8])(smem + 21568);      // 96
    int*    ctot    = (int*)(smem + 21664);               // 16
    int*    rtot    = (int*)(smem + 21680);               // 16

    const float wv = wT[m * N + tid];
    float p = px[m * N + tid];
    p += px[NM + m * N + tid];
    p += px[2 * NM + m * N + tid];
    p += px[3 * NM + m * N + tid];
    const float rv = p / sum_x[tid];
    worig[tid] = wv;
    if (tid < 256) { cnt[tid] = 0; rcnt[tid] = 0; cslot[tid] = 0; rslot[tid] = 0; rbmax[tid] = 0; }

    float pmv = wv;
    #pragma unroll
    for (int off = 1; off < 64; off <<= 1) {
        float o = __shfl_up(pmv, off, 64);
        if (lane >= off) pmv = fmaxf(pmv, o);
    }
    if (lane == 63) wtotmax[wid] = pmv;
    float wmn = wv, rmn = rv, rmx = rv;
    #pragma unroll
    for (int off = 32; off > 0; off >>= 1) {
        wmn = fminf(wmn, __shfl_xor(wmn, off, 64));
        rmn = fminf(rmn, __shfl_xor(rmn, off, 64));
        rmx = fmaxf(rmx, __shfl_xor(rmx, off, 64));
    }
    if (lane == 0) { red3[0][wid] = wmn; red3[1][wid] = rmn; red3[2][wid] = rmx; }
    __syncthreads();                                           // (1)

    {
        float om = -1e30f;
        for (int j = 0; j < wid; ++j) om = fmaxf(om, wtotmax[j]);
        pm[tid] = fmaxf(pmv, om);
    }
    float wmin = red3[0][0], rmin = red3[1][0], rmax = red3[2][0], wmax = wtotmax[0];
    #pragma unroll
    for (int j = 1; j < 8; ++j) {
        wmin = fminf(wmin, red3[0][j]);
        rmin = fminf(rmin, red3[1][j]);
        rmax = fmaxf(rmax, red3[2][j]);
        wmax = fmaxf(wmax, wtotmax[j]);
    }

    const float wscale = 255.0f / fmaxf(wmax - wmin, 1e-30f);
    int wk = (int)((wv - wmin) * wscale);
    wk = wk < 0 ? 0 : (wk > 255 ? 255 : wk);
    atomicAdd(&cnt[wk], 1);
    const float rscale = 255.0f / fmaxf(rmax - rmin, 1e-30f);
    int rk;
    { int kv = (int)((rv - rmin) * rscale); kv = kv < 0 ? 0 : (kv > 255 ? 255 : kv); rk = 255 - kv; }
    atomicAdd(&rcnt[rk], 1);
    atomicMax(&rbmax[rk], __float_as_int(rv));                 // rv > 0
    __syncthreads();                                           // (2)

    int myc = (tid < 256) ? cnt[tid] : rcnt[tid - 256];
    int incl = myc;
    #pragma unroll
    for (int off = 1; off < 64; off <<= 1) {
        int o = __shfl_up(incl, off, 64);
        if (lane >= off) incl += o;
    }
    if (lane == 63) { if (wid < 4) ctot[wid] = incl; else rtot[wid - 4] = incl; }
    __syncthreads();                                           // (3)
    if (tid < 256) {
        int eo = 0;
        for (int j = 0; j < wid; ++j) eo += ctot[j];
        cbase[tid] = eo + incl - myc;
    } else {
        int eo = 0, w2 = wid - 4;
        for (int j = 0; j < w2; ++j) eo += rtot[j];
        rbase[tid - 256] = eo + incl - myc;
    }
    __syncthreads();                                           // (4)

    { int p1 = cbase[wk] + atomicAdd(&cslot[wk], 1); wsrt[p1] = wv; }
    { int p2 = rbase[rk] + atomicAdd(&rslot[rk], 1);
      srx_r[p2] = rv; srx_n[p2] = tid; srx_u[p2] = __int_as_float(rbmax[rk]); }
    __syncthreads();                                           // (5)

    double bincl = 0.0, mysum = 0.0;
    if (tid < 256) {
        int st = cbase[tid], e = st + cnt[tid];
        for (int i = st; i < e; ++i) mysum += (double)wsrt[i];
        bincl = mysum;
        #pragma unroll
        for (int off = 1; off < 64; off <<= 1) {
            double o = __shfl_up(bincl, off, 64);
            if (lane >= off) bincl += o;
        }
        if (lane == 63) btot[wid] = bincl;
    }
    __syncthreads();                                           // (6)
    if (tid < 256) {
        double eo = 0.0;
        for (int j = 0; j < wid; ++j) eo += btot[j];
        bsumI[tid] = eo + bincl;
    }
    __syncthreads();                                           // (7)

    if (tid < 256) {
        // ==== phase C: ind_w scan (waves 0-3) ====
        const int b = tid;
        float bv = -1.0f; int bi = 0;
        for (int i = 0; i < 512; ++i) {
            float u = srx_u[i];
            if (__ballot(u >= bv) == 0ULL) break;
            float r = srx_r[i];
            int   n = srx_n[i];
            float xv = xT[n * B + b];                // coalesced
            float v = fminf(xv, r);
            if (v > bv || (v == bv && n < bi)) { bv = v; bi = n; }
        }
        out[BM + b * M + m] = fminf(x[b * N + bi], worig[bi]);   // chosen_w
    } else {
        // ==== phase D: rel_w CDF + ind_x (waves 4-7) ====
        const int b = tid - 256;
        const float tbm = tT[m * B + b];
        float btf = (tbm - wmin) * wscale;
        int kk; double S;
        if (btf < 0.0f) { kk = 0; S = 0.0; }
        else {
            int bt = (int)btf; bt = bt > 255 ? 255 : bt;
            kk = cbase[bt];
            S = (bt > 0) ? bsumI[bt - 1] : 0.0;
            int e = cbase[bt] + cnt[bt];
            for (int i = cbase[bt]; i < e; ++i) {
                float v = wsrt[i];
                if (v < tbm) { ++kk; S += (double)v; }
            }
        }
        double rw = S + (double)tbm * (double)(512 - kk);
        float c = (float)rw / sum_w[m];
        float tgt = fminf(c, pm[511]);
        int lo = 0, hi = 511;
        while (lo < hi) { int mid = (lo + hi) >> 1; if (pm[mid] >= tgt) hi = mid; else lo = mid + 1; }
        const int ind = lo;
        out[b * M + m] = fminf(x[b * N + ind], worig[ind]);      // chosen_x
    }
}

extern "C" void kernel_launch(void* const* d_in, const int* in_sizes, int n_in,
                              void* d_out, int out_size, void* d_ws, size_t ws_size,
                              hipStream_t stream) {
    const float* x = (const float*)d_in[0];  // (B, N)
    const float* w = (const float*)d_in[1];  // (N, M)
    const float* t = (const float*)d_in[2];  // (B, M)
    float* out = (float*)d_out;

    float* ws = (float*)d_ws;
    float* xT    = ws;                 // 131072 floats
    float* wT    = ws + 131072;        // 262144
    float* tT    = ws + 393216;        // 131072
    float* sum_x = ws + 524288;        // 512
    float* sum_w = ws + 524800;        // 512
    float* px    = ws + 525312;        // 4*NM = 1048576
    int*   flags = (int*)(ws + 1573888); // 512 ints

    hipMemsetAsync(flags, 0, 512 * sizeof(int), stream);
    k_fused<<<512, 512, 0, stream>>>(x, w, t, xT, wT, tT,
                                     sum_x, sum_w, px, flags, out);
}